// Round 1
// baseline (55.495 us; speedup 1.0000x reference)
//
#include <hip/hip_runtime.h>
#include <math.h>

// Problem constants (from reference)
#define NN      131072          // ROWS*COLS*P = 64*64*32
#define Q       10
#define T1      8
#define WHALF   3.5f            // WMAX/2

// d_out layout (float32, concatenated in return order):
//   [0, 10)                         prediction
//   [10, 10 + N*Q*T1)               voter_in[0]   (10,485,760)
//   [10 + N*Q*T1, ... + 2*N*Q*T1)   votes         (20,971,520)
#define VIN0_OFF   10u
#define VIN0_SZ    (NN * Q * T1)            // 10485760
#define VOTES_OFF  (VIN0_OFF + VIN0_SZ)     // 10485770
#define VOTES_SZ   (2u * NN * Q * T1)       // 20971520
#define E_F2       (VOTES_SZ / 2u)          // float2 elements of votes = 10,485,760

#define TALLY_SLOTS 32   // stripe global tally to reduce atomic contention

__global__ void dtnn_zero_tally(unsigned int* __restrict__ tally) {
    unsigned int t = threadIdx.x;
    if (t < Q * TALLY_SLOTS) tally[t] = 0u;
}

// One thread per float2 of `votes`. j -> (row r = j>>2, slot = j&3, t = {slot*2, slot*2+1}).
// r = (s*N + i)*Q + q. Stores are lane-consecutive float2 -> fully coalesced.
__global__ __launch_bounds__(256) void dtnn_main(
    const float* __restrict__ spikes,   // (N,) flattened
    const float* __restrict__ weights,  // (2, N, Q, T1)
    float* __restrict__ out,
    unsigned int* __restrict__ tally)   // (Q, TALLY_SLOTS)
{
    __shared__ unsigned int lt[Q];
    if (threadIdx.x < Q) lt[threadIdx.x] = 0u;
    __syncthreads();

    float2* __restrict__ votes2 = (float2*)(out + VOTES_OFF);
    float2* __restrict__ vin2   = (float2*)(out + VIN0_OFF);

    const unsigned int stride = gridDim.x * blockDim.x;
    for (unsigned int j = blockIdx.x * blockDim.x + threadIdx.x; j < E_F2; j += stride) {
        const unsigned int r    = j >> 2;          // (s,i,q) row
        const unsigned int slot = j & 3u;          // which float2 of the 8-bin row
        const unsigned int q    = r % Q;
        const unsigned int ri   = r / Q;           // s*N + i
        const unsigned int i    = ri & (NN - 1u);
        // s == (ri >> 17); equivalently r < NN*Q  <=>  s == 0

        float v = spikes[i];
        if (v >= 7.0f && !isinf(v)) v = 7.0f;      // clamp finite >= tau_eff
        const int  tv    = (int)v;
        const bool valid = (v >= 0.0f) && (v < 8.0f) && ((float)tv == v);
        const bool owns  = valid && ((unsigned)(tv >> 1) == slot);

        float2 o = make_float2(0.0f, 0.0f);
        if (owns) {
            const float w    = weights[r * 8u + (unsigned)tv];
            const float vote = (w >= WHALF) ? 1.0f : 0.0f;
            if (tv & 1) o.y = vote; else o.x = vote;
            if (vote != 0.0f) atomicAdd(&lt[q], 1u);
        }
        votes2[j] = o;

        if (r < NN * Q) {                          // s == 0: emit voter_in[0] row piece
            float2 h = make_float2(0.0f, 0.0f);
            if (owns) { if (tv & 1) h.y = 1.0f; else h.x = 1.0f; }
            vin2[j] = h;
        }
    }

    __syncthreads();
    if (threadIdx.x < Q) {
        atomicAdd(&tally[threadIdx.x * TALLY_SLOTS + (blockIdx.x & (TALLY_SLOTS - 1))],
                  lt[threadIdx.x]);
    }
}

__global__ void dtnn_pred(const unsigned int* __restrict__ tally, float* __restrict__ out) {
    __shared__ unsigned int sums[Q];
    const unsigned int t = threadIdx.x;
    if (t < Q) {
        unsigned int s = 0;
        #pragma unroll
        for (int k = 0; k < TALLY_SLOTS; ++k) s += tally[t * TALLY_SLOTS + k];
        sums[t] = s;
    }
    __syncthreads();
    if (t == 0) {
        unsigned int best = sums[0]; int bi = 0;
        #pragma unroll
        for (int q2 = 1; q2 < Q; ++q2) {
            if (sums[q2] > best) { best = sums[q2]; bi = q2; }  // first-argmax tie-break
        }
        #pragma unroll
        for (int q2 = 0; q2 < Q; ++q2) out[q2] = (q2 == bi) ? 1.0f : 0.0f;
    }
}

extern "C" void kernel_launch(void* const* d_in, const int* in_sizes, int n_in,
                              void* d_out, int out_size, void* d_ws, size_t ws_size,
                              hipStream_t stream) {
    const float* spikes  = (const float*)d_in[0];   // (64,64,32) float32
    const float* weights = (const float*)d_in[1];   // (2, N, Q, T1) float32
    float* out = (float*)d_out;
    unsigned int* tally = (unsigned int*)d_ws;      // Q * TALLY_SLOTS uints

    dtnn_zero_tally<<<1, 64 * ((Q * TALLY_SLOTS + 63) / 64), 0, stream>>>(tally);

    const int block = 256;
    const int grid  = 2048;   // grid-stride over 10,485,760 float2s (~20 iters/thread)
    dtnn_main<<<grid, block, 0, stream>>>(spikes, weights, out, tally);

    dtnn_pred<<<1, 64, 0, stream>>>(tally, out);
}